// Round 1
// baseline (449.672 us; speedup 1.0000x reference)
//
#include <hip/hip_runtime.h>
#include <math.h>

typedef unsigned short u16;
typedef __bf16 bf16x8 __attribute__((ext_vector_type(8)));
typedef float f32x4 __attribute__((ext_vector_type(4)));

#define LSEQ 2048
#define NB   4
#define NE   1024
#define NHEAD 8
#define ND1  2048
#define NHD  256
#define NM   8192          // LSEQ*NB
#define CRP  4104          // pitch of shifted-coeff rows (elements, mult of 8)

__device__ __forceinline__ u16 f2bf(float f) {
  unsigned u = __float_as_uint(f);
  u += 0x7FFFu + ((u >> 16) & 1u);       // RTNE
  return (u16)(u >> 16);
}
__device__ __forceinline__ float bf2f(u16 h) {
  return __uint_as_float(((unsigned)h) << 16);
}

// async global->LDS, 16B per lane; LDS dest is wave-uniform base + lane*16B
__device__ __forceinline__ void gl_lds16(const u16* g, u16* l) {
  __builtin_amdgcn_global_load_lds(
      (const __attribute__((address_space(1))) void*)g,
      (__attribute__((address_space(3))) void*)l, 16, 0, 0);
}

// ---------------- f32 -> bf16 bulk convert (n4 = n/4 float4s) ----------------
__global__ __launch_bounds__(256) void cvt_kernel(const float* __restrict__ src,
                                                  u16* __restrict__ dst, int n4) {
  int i = blockIdx.x * 256 + threadIdx.x;
  if (i < n4) {
    float4 v = ((const float4*)src)[i];
    ushort4 o;
    o.x = f2bf(v.x); o.y = f2bf(v.y); o.z = f2bf(v.z); o.w = f2bf(v.w);
    ((ushort4*)dst)[i] = o;
  }
}

// ---------------- build 8 shifted copies of reversed toeplitz coeffs ----------
// cr[h][mm] = c_h[4094-mm] where c_h[t+2047]= (t==0? zero : t>0? pos[t-1] : neg[-t-1])
// cr8[(h*8+s)][m] = cr[h][m+s]  (0 beyond 4094), pitch CRP.
__global__ __launch_bounds__(256) void build_cr8(const float* __restrict__ pos,
                                                 const float* __restrict__ zero,
                                                 const float* __restrict__ neg,
                                                 u16* __restrict__ cr8) {
  int h = blockIdx.x >> 3, s = blockIdx.x & 7;
  u16* out = cr8 + (size_t)blockIdx.x * CRP;
  for (int m = threadIdx.x; m < CRP; m += 256) {
    int mm = m + s;
    float val = 0.f;
    if (mm <= 4094) {
      int t = 2047 - mm;                  // t = i - j
      if (t == 0)      val = zero[h];
      else if (t > 0)  val = pos[h * (LSEQ - 1) + t - 1];
      else             val = neg[h * (LSEQ - 1) + (-t) - 1];
    }
    out[m] = f2bf(val);
  }
}

// ---------------- RMSNorm: x = q / (||q||/sqrt(E) + 1e-8), bf16 out ----------
__global__ __launch_bounds__(256) void rmsnorm_kernel(const float* __restrict__ q,
                                                      u16* __restrict__ x) {
  int row = blockIdx.x;
  float4 v = ((const float4*)(q + (size_t)row * NE))[threadIdx.x];
  float ss = v.x * v.x + v.y * v.y + v.z * v.z + v.w * v.w;
  #pragma unroll
  for (int off = 32; off > 0; off >>= 1) ss += __shfl_down(ss, off, 64);
  __shared__ float wss[4];
  int wave = threadIdx.x >> 6, lane = threadIdx.x & 63;
  if (lane == 0) wss[wave] = ss;
  __syncthreads();
  float tot = wss[0] + wss[1] + wss[2] + wss[3];
  float scale = 1.f / (sqrtf(tot) * 0.03125f + 1e-8f);
  ushort4 o;
  o.x = f2bf(v.x * scale); o.y = f2bf(v.y * scale);
  o.z = f2bf(v.z * scale); o.w = f2bf(v.w * scale);
  ((ushort4*)(x + (size_t)row * NE))[threadIdx.x] = o;
}

// ---------------- transpose v (rows (j,b), cols (h,d)) -> vT[h][b*256+d][j] --
__global__ __launch_bounds__(256) void transpose_v(const u16* __restrict__ v,
                                                   u16* __restrict__ vT) {
  __shared__ u16 s[64 * 66];
  int j0 = blockIdx.x * 64, d0 = blockIdx.y * 64;
  int h = blockIdx.z >> 2, b = blockIdx.z & 3;
  #pragma unroll
  for (int it = 0; it < 16; ++it) {
    int idx = threadIdx.x + 256 * it;
    int r = idx >> 6, c = idx & 63;
    s[r * 66 + c] = v[((size_t)(j0 + r) * NB + b) * ND1 + h * NHD + d0 + c];
  }
  __syncthreads();
  #pragma unroll
  for (int it = 0; it < 16; ++it) {
    int idx = threadIdx.x + 256 * it;
    int r = idx >> 6, c = idx & 63;
    vT[((size_t)h * (NB * NHD) + b * NHD + d0 + r) * LSEQ + j0 + c] = s[c * 66 + r];
  }
}

// ---------------- generic 128x128 MFMA GEMM, C = A(MxK) * W(NxK)^T -----------
// m97 structure: global_load_lds width=16 staging into LINEAR LDS (LDA=64),
// 2-barrier K-loop, 4 waves, acc[4][4] of 16x16x32 bf16 MFMA.
// MODE 0: C(bf16) = silu(acc + bias[n])                     (u/v projections)
// MODE 1: A staged from cr8 (toeplitz), epilogue u *= acc   (head GEMM, z=u*y)
// MODE 2: Cf(f32) = acc + bias[n] + resid[m*N+n]            (output GEMM)
template <int MODE>
__global__ __launch_bounds__(256) void gemm_kernel(
    const u16* __restrict__ A, const u16* __restrict__ Bw,
    const float* __restrict__ bias, const float* __restrict__ resid,
    u16* __restrict__ Cbf, float* __restrict__ Cf,
    int Msz, int Nsz, int Ksz) {
  __shared__ __align__(16) u16 As[128 * 64];
  __shared__ __align__(16) u16 Ws[128 * 64];

  const int tid = threadIdx.x;
  const int lane = tid & 63, wave = tid >> 6;
  const int wr = (wave >> 1) * 64, wc = (wave & 1) * 64;
  const int lr = lane & 15, lq = lane >> 4;
  const int i0 = blockIdx.y * 128, n0 = blockIdx.x * 128;

  const u16* Bh = Bw;
  const u16* Acr = A;
  if (MODE == 1) {
    Bh  = Bw + (size_t)blockIdx.z * Nsz * Ksz;   // vT head base
    Acr = A + (size_t)blockIdx.z * 8 * CRP;      // cr8 head base
  }

  f32x4 acc[4][4];
  #pragma unroll
  for (int a = 0; a < 4; ++a)
    #pragma unroll
    for (int b = 0; b < 4; ++b) acc[a][b] = (f32x4){0.f, 0.f, 0.f, 0.f};

  const int nkt = Ksz >> 6;
  for (int kt = 0; kt < nkt; ++kt) {
    // ---- stage A tile (128 x 64) : DMA global->LDS, 16B/lane ----
    #pragma unroll
    for (int it = 0; it < 4; ++it) {
      int vv = tid + 256 * it;
      int r = vv >> 3, c8 = vv & 7;
      const u16* src;
      if (MODE != 1) {
        src = A + (size_t)(i0 + r) * Ksz + kt * 64 + c8 * 8;
      } else {
        int p = 2047 - (i0 + r) + kt * 64;       // cr index of column 0
        int s = p & 7, qq = p - s;               // 8-aligned base in copy s
        src = Acr + (size_t)s * CRP + qq + c8 * 8;
      }
      gl_lds16(src, &As[(size_t)(wave * 64 + it * 256) * 8]);
    }
    // ---- stage W tile (128 x 64) ----
    #pragma unroll
    for (int it = 0; it < 4; ++it) {
      int vv = tid + 256 * it;
      int r = vv >> 3, c8 = vv & 7;
      gl_lds16(Bh + (size_t)(n0 + r) * Ksz + kt * 64 + c8 * 8,
               &Ws[(size_t)(wave * 64 + it * 256) * 8]);
    }
    __syncthreads();
    #pragma unroll
    for (int ks = 0; ks < 2; ++ks) {
      bf16x8 af[4], bfr[4];
      #pragma unroll
      for (int rt = 0; rt < 4; ++rt)
        af[rt] = *(const bf16x8*)&As[(wr + rt * 16 + lr) * 64 + ks * 32 + lq * 8];
      #pragma unroll
      for (int ct = 0; ct < 4; ++ct)
        bfr[ct] = *(const bf16x8*)&Ws[(wc + ct * 16 + lr) * 64 + ks * 32 + lq * 8];
      #pragma unroll
      for (int rt = 0; rt < 4; ++rt)
        #pragma unroll
        for (int ct = 0; ct < 4; ++ct)
          acc[rt][ct] = __builtin_amdgcn_mfma_f32_16x16x32_bf16(
              af[rt], bfr[ct], acc[rt][ct], 0, 0, 0);
    }
    __syncthreads();
  }

  // ---- epilogue ----
  #pragma unroll
  for (int rt = 0; rt < 4; ++rt) {
    #pragma unroll
    for (int ct = 0; ct < 4; ++ct) {
      int col = n0 + wc + ct * 16 + lr;
      #pragma unroll
      for (int reg = 0; reg < 4; ++reg) {
        int row = i0 + wr + rt * 16 + lq * 4 + reg;
        float yv = acc[rt][ct][reg];
        if (MODE == 0) {
          float t = yv + bias[col];
          t = t / (1.f + __expf(-t));            // silu
          Cbf[(size_t)row * Nsz + col] = f2bf(t);
        } else if (MODE == 1) {
          int b = col >> 8, d = col & 255;       // col = b*256 + d
          size_t ui = ((size_t)row * NB + b) * ND1 + (size_t)blockIdx.z * NHD + d;
          float uv = bf2f(Cbf[ui]);
          Cbf[ui] = f2bf(uv * yv);               // z = u * y, in place
        } else {
          size_t oi = (size_t)row * Nsz + col;
          Cf[oi] = yv + bias[col] + resid[oi];
        }
      }
    }
  }
}

extern "C" void kernel_launch(void* const* d_in, const int* in_sizes, int n_in,
                              void* d_out, int out_size, void* d_ws, size_t ws_size,
                              hipStream_t stream) {
  const float* q    = (const float*)d_in[0];
  const float* uw   = (const float*)d_in[3];
  const float* ub   = (const float*)d_in[4];
  const float* vw   = (const float*)d_in[5];
  const float* vb   = (const float*)d_in[6];
  const float* ow   = (const float*)d_in[7];
  const float* ob   = (const float*)d_in[8];
  const float* pos  = (const float*)d_in[9];
  const float* zero = (const float*)d_in[10];
  const float* neg  = (const float*)d_in[11];
  float* out = (float*)d_out;

  char* ws = (char*)d_ws;
  u16* x   = (u16*)(ws + 0);            // 8192x1024 bf16 = 16 MiB
  u16* uwb = (u16*)(ws + 16777216);     // 4 MiB
  u16* vwb = (u16*)(ws + 20971520);     // 4 MiB
  u16* owb = (u16*)(ws + 25165824);     // 4 MiB
  u16* u   = (u16*)(ws + 29360128);     // 8192x2048 bf16 = 32 MiB (later z)
  u16* v   = (u16*)(ws + 62914560);     // 32 MiB
  u16* vT  = (u16*)(ws + 96468992);     // 32 MiB
  u16* cr8 = (u16*)(ws + 130023424);    // 8*8*4104*2 = 513 KiB

  cvt_kernel<<<2048, 256, 0, stream>>>(uw, uwb, 524288);
  cvt_kernel<<<2048, 256, 0, stream>>>(vw, vwb, 524288);
  cvt_kernel<<<2048, 256, 0, stream>>>(ow, owb, 524288);
  build_cr8<<<64, 256, 0, stream>>>(pos, zero, neg, cr8);
  rmsnorm_kernel<<<NM, 256, 0, stream>>>(q, x);

  // u = silu(x @ uw^T + ub), v = silu(x @ vw^T + vb)
  gemm_kernel<0><<<dim3(16, 64, 1), 256, 0, stream>>>(x, uwb, ub, nullptr, u, nullptr,
                                                      NM, ND1, NE);
  gemm_kernel<0><<<dim3(16, 64, 1), 256, 0, stream>>>(x, vwb, vb, nullptr, v, nullptr,
                                                      NM, ND1, NE);
  // vT[h][b*256+d][j] = v[(j,b)][h*256+d]
  transpose_v<<<dim3(32, 4, 32), 256, 0, stream>>>(v, vT);
  // per head: y = T_h @ vT_h^T ; z = u*y in place (in u buffer)
  gemm_kernel<1><<<dim3(8, 16, 8), 256, 0, stream>>>(cr8, vT, nullptr, nullptr, u, nullptr,
                                                     LSEQ, NB * NHD, LSEQ);
  // out = z @ ow^T + ob + q
  gemm_kernel<2><<<dim3(8, 64, 1), 256, 0, stream>>>(u, owb, ob, q, nullptr, out,
                                                     NM, NE, ND1);
}

// Round 2
// 407.599 us; speedup vs baseline: 1.1032x; 1.1032x over previous
//
#include <hip/hip_runtime.h>
#include <math.h>

typedef unsigned short u16;
typedef __bf16 bf16x8 __attribute__((ext_vector_type(8)));
typedef float f32x4 __attribute__((ext_vector_type(4)));

#define LSEQ 2048
#define NB   4
#define NE   1024
#define NHEAD 8
#define ND1  2048
#define NHD  256
#define NM   8192          // LSEQ*NB
#define CRP  4104          // pitch of shifted-coeff rows (elements, mult of 8)

__device__ __forceinline__ u16 f2bf(float f) {
  unsigned u = __float_as_uint(f);
  u += 0x7FFFu + ((u >> 16) & 1u);       // RTNE
  return (u16)(u >> 16);
}
__device__ __forceinline__ float bf2f(u16 h) {
  return __uint_as_float(((unsigned)h) << 16);
}

// async global->LDS, 16B per lane; LDS dest is wave-uniform base + lane*16B
__device__ __forceinline__ void gl_lds16(const u16* g, u16* l) {
  __builtin_amdgcn_global_load_lds(
      (const __attribute__((address_space(1))) void*)g,
      (__attribute__((address_space(3))) void*)l, 16, 0, 0);
}

// ---------------- f32 -> bf16 bulk convert (n4 = n/4 float4s) ----------------
__global__ __launch_bounds__(256) void cvt_kernel(const float* __restrict__ src,
                                                  u16* __restrict__ dst, int n4) {
  int i = blockIdx.x * 256 + threadIdx.x;
  if (i < n4) {
    float4 v = ((const float4*)src)[i];
    ushort4 o;
    o.x = f2bf(v.x); o.y = f2bf(v.y); o.z = f2bf(v.z); o.w = f2bf(v.w);
    ((ushort4*)dst)[i] = o;
  }
}

// ---------------- build 8 shifted copies of reversed toeplitz coeffs ----------
// cr[h][mm] = c_h[4094-mm] where c_h[t+2047]= (t==0? zero : t>0? pos[t-1] : neg[-t-1])
// cr8[(h*8+s)][m] = cr[h][m+s]  (0 beyond 4094), pitch CRP.
__global__ __launch_bounds__(256) void build_cr8(const float* __restrict__ pos,
                                                 const float* __restrict__ zero,
                                                 const float* __restrict__ neg,
                                                 u16* __restrict__ cr8) {
  int h = blockIdx.x >> 3, s = blockIdx.x & 7;
  u16* out = cr8 + (size_t)blockIdx.x * CRP;
  for (int m = threadIdx.x; m < CRP; m += 256) {
    int mm = m + s;
    float val = 0.f;
    if (mm <= 4094) {
      int t = 2047 - mm;                  // t = i - j
      if (t == 0)      val = zero[h];
      else if (t > 0)  val = pos[h * (LSEQ - 1) + t - 1];
      else             val = neg[h * (LSEQ - 1) + (-t) - 1];
    }
    out[m] = f2bf(val);
  }
}

// ---------------- RMSNorm: x = q / (||q||/sqrt(E) + 1e-8), bf16 out ----------
__global__ __launch_bounds__(256) void rmsnorm_kernel(const float* __restrict__ q,
                                                      u16* __restrict__ x) {
  int row = blockIdx.x;
  float4 v = ((const float4*)(q + (size_t)row * NE))[threadIdx.x];
  float ss = v.x * v.x + v.y * v.y + v.z * v.z + v.w * v.w;
  #pragma unroll
  for (int off = 32; off > 0; off >>= 1) ss += __shfl_down(ss, off, 64);
  __shared__ float wss[4];
  int wave = threadIdx.x >> 6, lane = threadIdx.x & 63;
  if (lane == 0) wss[wave] = ss;
  __syncthreads();
  float tot = wss[0] + wss[1] + wss[2] + wss[3];
  float scale = 1.f / (sqrtf(tot) * 0.03125f + 1e-8f);
  ushort4 o;
  o.x = f2bf(v.x * scale); o.y = f2bf(v.y * scale);
  o.z = f2bf(v.z * scale); o.w = f2bf(v.w * scale);
  ((ushort4*)(x + (size_t)row * NE))[threadIdx.x] = o;
}

// ---------------- transpose v (rows (j,b), cols (h,d)) -> vT[h][b*256+d][j] --
__global__ __launch_bounds__(256) void transpose_v(const u16* __restrict__ v,
                                                   u16* __restrict__ vT) {
  __shared__ u16 s[64 * 66];
  int j0 = blockIdx.x * 64, d0 = blockIdx.y * 64;
  int h = blockIdx.z >> 2, b = blockIdx.z & 3;
  #pragma unroll
  for (int it = 0; it < 16; ++it) {
    int idx = threadIdx.x + 256 * it;
    int r = idx >> 6, c = idx & 63;
    s[r * 66 + c] = v[((size_t)(j0 + r) * NB + b) * ND1 + h * NHD + d0 + c];
  }
  __syncthreads();
  #pragma unroll
  for (int it = 0; it < 16; ++it) {
    int idx = threadIdx.x + 256 * it;
    int r = idx >> 6, c = idx & 63;
    vT[((size_t)h * (NB * NHD) + b * NHD + d0 + r) * LSEQ + j0 + c] = s[c * 66 + r];
  }
}

// ---------------- generic 128x128 MFMA GEMM, C = A(MxK) * W(NxK)^T -----------
// m97 structure + rule #21 both-sides swizzle:
//  - global_load_lds w=16 into LINEAR LDS (row = 64 bf16 = 128 B, 8 chunks of 16 B)
//  - LDS slot (r, q) holds logical chunk q ^ (r&7)  (achieved by pre-swizzling
//    the per-lane GLOBAL source address; LDS dest stays lane-linear)
//  - ds_read applies the same XOR -> 16-way read conflict becomes 2-way (free)
// MODE 0: C(bf16) = silu(acc + bias[n])                     (u/v projections)
// MODE 1: A staged from cr8 (toeplitz), epilogue u *= acc   (head GEMM, z=u*y)
// MODE 2: Cf(f32) = acc + bias[n] + resid[m*N+n]            (output GEMM)
template <int MODE>
__global__ __launch_bounds__(256) void gemm_kernel(
    const u16* __restrict__ A, const u16* __restrict__ Bw,
    const float* __restrict__ bias, const float* __restrict__ resid,
    u16* __restrict__ Cbf, float* __restrict__ Cf,
    int Msz, int Nsz, int Ksz) {
  __shared__ __align__(16) u16 As[128 * 64];
  __shared__ __align__(16) u16 Ws[128 * 64];

  const int tid = threadIdx.x;
  const int lane = tid & 63, wave = tid >> 6;
  const int wr = (wave >> 1) * 64, wc = (wave & 1) * 64;
  const int lr = lane & 15, lq = lane >> 4;
  const int i0 = blockIdx.y * 128, n0 = blockIdx.x * 128;

  const u16* Bh = Bw;
  const u16* Acr = A;
  if (MODE == 1) {
    Bh  = Bw + (size_t)blockIdx.z * Nsz * Ksz;   // vT head base
    Acr = A + (size_t)blockIdx.z * 8 * CRP;      // cr8 head base
  }

  f32x4 acc[4][4];
  #pragma unroll
  for (int a = 0; a < 4; ++a)
    #pragma unroll
    for (int b = 0; b < 4; ++b) acc[a][b] = (f32x4){0.f, 0.f, 0.f, 0.f};

  const int nkt = Ksz >> 6;
  for (int kt = 0; kt < nkt; ++kt) {
    // ---- stage A tile (128 x 64) : DMA global->LDS, 16B/lane ----
    // LDS slot (r, c8) receives global chunk c8 ^ (r&7)  (swizzled source)
    #pragma unroll
    for (int it = 0; it < 4; ++it) {
      int vv = tid + 256 * it;
      int r = vv >> 3, c8 = vv & 7;
      int c8s = c8 ^ (r & 7);
      const u16* src;
      if (MODE != 1) {
        src = A + (size_t)(i0 + r) * Ksz + kt * 64 + c8s * 8;
      } else {
        int p = 2047 - (i0 + r) + kt * 64;       // cr index of column 0
        int s = p & 7, qq = p - s;               // 8-aligned base in copy s
        src = Acr + (size_t)s * CRP + qq + c8s * 8;
      }
      gl_lds16(src, &As[(size_t)(wave * 64 + it * 256) * 8]);
    }
    // ---- stage W tile (128 x 64) ----
    #pragma unroll
    for (int it = 0; it < 4; ++it) {
      int vv = tid + 256 * it;
      int r = vv >> 3, c8 = vv & 7;
      int c8s = c8 ^ (r & 7);
      gl_lds16(Bh + (size_t)(n0 + r) * Ksz + kt * 64 + c8s * 8,
               &Ws[(size_t)(wave * 64 + it * 256) * 8]);
    }
    __syncthreads();
    #pragma unroll
    for (int ks = 0; ks < 2; ++ks) {
      bf16x8 af[4], bfr[4];
      #pragma unroll
      for (int rt = 0; rt < 4; ++rt) {
        int ar = wr + rt * 16 + lr;
        int cq = (ks * 4 + lq) ^ (ar & 7);       // swizzled chunk on read
        af[rt] = *(const bf16x8*)&As[ar * 64 + cq * 8];
      }
      #pragma unroll
      for (int ct = 0; ct < 4; ++ct) {
        int br = wc + ct * 16 + lr;
        int cq = (ks * 4 + lq) ^ (br & 7);
        bfr[ct] = *(const bf16x8*)&Ws[br * 64 + cq * 8];
      }
      #pragma unroll
      for (int rt = 0; rt < 4; ++rt)
        #pragma unroll
        for (int ct = 0; ct < 4; ++ct)
          acc[rt][ct] = __builtin_amdgcn_mfma_f32_16x16x32_bf16(
              af[rt], bfr[ct], acc[rt][ct], 0, 0, 0);
    }
    __syncthreads();
  }

  // ---- epilogue ----
  #pragma unroll
  for (int rt = 0; rt < 4; ++rt) {
    #pragma unroll
    for (int ct = 0; ct < 4; ++ct) {
      int col = n0 + wc + ct * 16 + lr;
      #pragma unroll
      for (int reg = 0; reg < 4; ++reg) {
        int row = i0 + wr + rt * 16 + lq * 4 + reg;
        float yv = acc[rt][ct][reg];
        if (MODE == 0) {
          float t = yv + bias[col];
          t = t / (1.f + __expf(-t));            // silu
          Cbf[(size_t)row * Nsz + col] = f2bf(t);
        } else if (MODE == 1) {
          int b = col >> 8, d = col & 255;       // col = b*256 + d
          size_t ui = ((size_t)row * NB + b) * ND1 + (size_t)blockIdx.z * NHD + d;
          float uv = bf2f(Cbf[ui]);
          Cbf[ui] = f2bf(uv * yv);               // z = u * y, in place
        } else {
          size_t oi = (size_t)row * Nsz + col;
          Cf[oi] = yv + bias[col] + resid[oi];
        }
      }
    }
  }
}

extern "C" void kernel_launch(void* const* d_in, const int* in_sizes, int n_in,
                              void* d_out, int out_size, void* d_ws, size_t ws_size,
                              hipStream_t stream) {
  const float* q    = (const float*)d_in[0];
  const float* uw   = (const float*)d_in[3];
  const float* ub   = (const float*)d_in[4];
  const float* vw   = (const float*)d_in[5];
  const float* vb   = (const float*)d_in[6];
  const float* ow   = (const float*)d_in[7];
  const float* ob   = (const float*)d_in[8];
  const float* pos  = (const float*)d_in[9];
  const float* zero = (const float*)d_in[10];
  const float* neg  = (const float*)d_in[11];
  float* out = (float*)d_out;

  char* ws = (char*)d_ws;
  u16* x   = (u16*)(ws + 0);            // 8192x1024 bf16 = 16 MiB
  u16* uwb = (u16*)(ws + 16777216);     // 4 MiB
  u16* vwb = (u16*)(ws + 20971520);     // 4 MiB
  u16* owb = (u16*)(ws + 25165824);     // 4 MiB
  u16* u   = (u16*)(ws + 29360128);     // 8192x2048 bf16 = 32 MiB (later z)
  u16* v   = (u16*)(ws + 62914560);     // 32 MiB
  u16* vT  = (u16*)(ws + 96468992);     // 32 MiB
  u16* cr8 = (u16*)(ws + 130023424);    // 8*8*4104*2 = 513 KiB

  cvt_kernel<<<2048, 256, 0, stream>>>(uw, uwb, 524288);
  cvt_kernel<<<2048, 256, 0, stream>>>(vw, vwb, 524288);
  cvt_kernel<<<2048, 256, 0, stream>>>(ow, owb, 524288);
  build_cr8<<<64, 256, 0, stream>>>(pos, zero, neg, cr8);
  rmsnorm_kernel<<<NM, 256, 0, stream>>>(q, x);

  // u = silu(x @ uw^T + ub), v = silu(x @ vw^T + vb)
  gemm_kernel<0><<<dim3(16, 64, 1), 256, 0, stream>>>(x, uwb, ub, nullptr, u, nullptr,
                                                      NM, ND1, NE);
  gemm_kernel<0><<<dim3(16, 64, 1), 256, 0, stream>>>(x, vwb, vb, nullptr, v, nullptr,
                                                      NM, ND1, NE);
  // vT[h][b*256+d][j] = v[(j,b)][h*256+d]
  transpose_v<<<dim3(32, 4, 32), 256, 0, stream>>>(v, vT);
  // per head: y = T_h @ vT_h^T ; z = u*y in place (in u buffer)
  gemm_kernel<1><<<dim3(8, 16, 8), 256, 0, stream>>>(cr8, vT, nullptr, nullptr, u, nullptr,
                                                     LSEQ, NB * NHD, LSEQ);
  // out = z @ ow^T + ob + q
  gemm_kernel<2><<<dim3(8, 64, 1), 256, 0, stream>>>(u, owb, ob, q, nullptr, out,
                                                     NM, NE, ND1);
}

// Round 4
// 373.157 us; speedup vs baseline: 1.2050x; 1.0923x over previous
//
#include <hip/hip_runtime.h>
#include <math.h>

typedef unsigned short u16;
typedef __bf16 bf16x8 __attribute__((ext_vector_type(8)));
typedef float f32x4 __attribute__((ext_vector_type(4)));

#define LSEQ 2048
#define NB   4
#define NE   1024
#define NHEAD 8
#define ND1  2048
#define NHD  256
#define NM   8192          // LSEQ*NB
#define CRP  4104          // pitch of shifted-coeff rows (elements, mult of 8)

__device__ __forceinline__ u16 f2bf(float f) {
  unsigned u = __float_as_uint(f);
  u += 0x7FFFu + ((u >> 16) & 1u);       // RTNE
  return (u16)(u >> 16);
}
__device__ __forceinline__ float bf2f(u16 h) {
  return __uint_as_float(((unsigned)h) << 16);
}

// async global->LDS, 16B per lane; LDS dest is wave-uniform base + lane*16B
__device__ __forceinline__ void gl_lds16(const u16* g, u16* l) {
  __builtin_amdgcn_global_load_lds(
      (const __attribute__((address_space(1))) void*)g,
      (__attribute__((address_space(3))) void*)l, 16, 0, 0);
}

// ---------------- f32 -> bf16 bulk convert (n4 = n/4 float4s) ----------------
__global__ __launch_bounds__(256) void cvt_kernel(const float* __restrict__ src,
                                                  u16* __restrict__ dst, int n4) {
  int i = blockIdx.x * 256 + threadIdx.x;
  if (i < n4) {
    float4 v = ((const float4*)src)[i];
    ushort4 o;
    o.x = f2bf(v.x); o.y = f2bf(v.y); o.z = f2bf(v.z); o.w = f2bf(v.w);
    ((ushort4*)dst)[i] = o;
  }
}

// ---------------- build 8 shifted copies of reversed toeplitz coeffs ----------
__global__ __launch_bounds__(256) void build_cr8(const float* __restrict__ pos,
                                                 const float* __restrict__ zero,
                                                 const float* __restrict__ neg,
                                                 u16* __restrict__ cr8) {
  int h = blockIdx.x >> 3, s = blockIdx.x & 7;
  u16* out = cr8 + (size_t)blockIdx.x * CRP;
  for (int m = threadIdx.x; m < CRP; m += 256) {
    int mm = m + s;
    float val = 0.f;
    if (mm <= 4094) {
      int t = 2047 - mm;                  // t = i - j
      if (t == 0)      val = zero[h];
      else if (t > 0)  val = pos[h * (LSEQ - 1) + t - 1];
      else             val = neg[h * (LSEQ - 1) + (-t) - 1];
    }
    out[m] = f2bf(val);
  }
}

// ---------------- RMSNorm: x = q / (||q||/sqrt(E) + 1e-8), bf16 out ----------
__global__ __launch_bounds__(256) void rmsnorm_kernel(const float* __restrict__ q,
                                                      u16* __restrict__ x) {
  int row = blockIdx.x;
  float4 v = ((const float4*)(q + (size_t)row * NE))[threadIdx.x];
  float ss = v.x * v.x + v.y * v.y + v.z * v.z + v.w * v.w;
  #pragma unroll
  for (int off = 32; off > 0; off >>= 1) ss += __shfl_down(ss, off, 64);
  __shared__ float wss[4];
  int wave = threadIdx.x >> 6, lane = threadIdx.x & 63;
  if (lane == 0) wss[wave] = ss;
  __syncthreads();
  float tot = wss[0] + wss[1] + wss[2] + wss[3];
  float scale = 1.f / (sqrtf(tot) * 0.03125f + 1e-8f);
  ushort4 o;
  o.x = f2bf(v.x * scale); o.y = f2bf(v.y * scale);
  o.z = f2bf(v.z * scale); o.w = f2bf(v.w * scale);
  ((ushort4*)(x + (size_t)row * NE))[threadIdx.x] = o;
}

// ---------------- transpose v (rows (j,b), cols (h,d)) -> vT[h][b*256+d][j] --
__global__ __launch_bounds__(256) void transpose_v(const u16* __restrict__ v,
                                                   u16* __restrict__ vT) {
  __shared__ u16 s[64 * 66];
  int j0 = blockIdx.x * 64, d0 = blockIdx.y * 64;
  int h = blockIdx.z >> 2, b = blockIdx.z & 3;
  #pragma unroll
  for (int it = 0; it < 16; ++it) {
    int idx = threadIdx.x + 256 * it;
    int r = idx >> 6, c = idx & 63;
    s[r * 66 + c] = v[((size_t)(j0 + r) * NB + b) * ND1 + h * NHD + d0 + c];
  }
  __syncthreads();
  #pragma unroll
  for (int it = 0; it < 16; ++it) {
    int idx = threadIdx.x + 256 * it;
    int r = idx >> 6, c = idx & 63;
    vT[((size_t)h * (NB * NHD) + b * NHD + d0 + r) * LSEQ + j0 + c] = s[c * 66 + r];
  }
}

// ================= 256x256 8-phase GEMM (T2+T3+T4+T5), C = A * W^T ==========
// 8 waves (2Mx4N), per-wave 128x64 output, BK=64, 128 KiB LDS double-buffer.
// XOR swizzle: LDS slot (r, s) holds row-chunk s ^ (r&7); achieved by
// pre-swizzling the per-lane GLOBAL source (gl_lds dest stays lane-linear),
// same XOR applied on ds_read (round-2 verified: 0 bank conflicts).
// Stage stream per tile tt: P1:A0(tt+1) P2:A1(tt+1) -> buf^1 (dead tenant)
//                           P3:B0(tt+2) P4:B1(tt+2) -> B region freed at P2.
// vmcnt ledger: entry(tt) in-flight = B(tt+1) [4 loads]; P4 waits vmcnt(4)
// -> retires B(tt+1)+A(tt+1), leaves B(tt+2). vmcnt(0) only at tt==nkt-2.

__device__ __forceinline__ bf16x8 ldsfrag(const u16* buf, int rr, int q) {
  return *(const bf16x8*)(buf + rr * 64 + ((q ^ (rr & 7)) * 8));
}

template <int MODE>
__device__ __forceinline__ void stage_Ah(const u16* A, const u16* Acr, int Ksz,
                                         int i0, int kt, int half, u16* dstbuf,
                                         int tid) {
  int wave = tid >> 6;
  #pragma unroll
  for (int it = 0; it < 2; ++it) {
    int vv = it * 512 + tid;               // 0..1023
    int r = vv >> 3, c8 = vv & 7, c8s = c8 ^ (r & 7);
    int row = i0 + half * 128 + r;
    const u16* src;
    if (MODE != 1) {
      src = A + (size_t)row * Ksz + kt * 64 + c8s * 8;
    } else {
      int p = 2047 - row + kt * 64;        // cr index of column 0
      int s = p & 7, qq = p - s;           // 8-aligned base in copy s
      src = Acr + (size_t)s * CRP + qq + c8s * 8;
    }
    // dest: half-tile base (u16 units) + per-(it,wave) chunk base; lane adds 16B
    gl_lds16(src, dstbuf + half * 8192 + (it * 512 + wave * 64) * 8);
  }
}

__device__ __forceinline__ void stage_Bh(const u16* B, int Ksz, int n0, int kt,
                                         int half, u16* dstbuf, int tid) {
  int wave = tid >> 6;
  #pragma unroll
  for (int it = 0; it < 2; ++it) {
    int vv = it * 512 + tid;
    int r = vv >> 3, c8 = vv & 7, c8s = c8 ^ (r & 7);
    gl_lds16(B + (size_t)(n0 + half * 128 + r) * Ksz + kt * 64 + c8s * 8,
             dstbuf + half * 8192 + (it * 512 + wave * 64) * 8);
  }
}

#define PHASE_MID()                                        \
  __builtin_amdgcn_s_barrier();                            \
  asm volatile("s_waitcnt lgkmcnt(0)" ::: "memory");       \
  __builtin_amdgcn_sched_barrier(0);                       \
  __builtin_amdgcn_s_setprio(1);

#define PHASE_END()                                        \
  __builtin_amdgcn_s_setprio(0);                           \
  __builtin_amdgcn_s_barrier();                            \
  __builtin_amdgcn_sched_barrier(0);

// MODE 0: Cbf = silu(acc + bias[n])        (u/v projections)
// MODE 1: A from cr8 (toeplitz), epilogue Cbf[ui] *= acc   (z = u*y in place)
template <int MODE>
__global__ __launch_bounds__(512, 2) void gemm256(
    const u16* __restrict__ A, const u16* __restrict__ Bw,
    const float* __restrict__ bias, u16* __restrict__ Cbf,
    int Msz, int Nsz, int Ksz) {
  extern __shared__ __align__(16) u16 lds[];
  u16* As = lds;             // 2 buf x 256 x 64 = 32768 u16
  u16* Ws = lds + 32768;     // 2 buf x 256 x 64

  const int tid = threadIdx.x;
  const int lane = tid & 63, wave = tid >> 6;
  const int wr = (wave >> 2) * 128, wc = (wave & 3) * 64;
  const int lr = lane & 15, lq = lane >> 4;
  const int i0 = blockIdx.y * 256, n0 = blockIdx.x * 256;

  const u16* Bh = Bw;
  const u16* Acr = A;
  if (MODE == 1) {
    Bh  = Bw + (size_t)blockIdx.z * Nsz * Ksz;   // vT head base
    Acr = A + (size_t)blockIdx.z * 8 * CRP;      // cr8 head base
  }
  const int nkt = Ksz >> 6;

  f32x4 acc[8][4];
  #pragma unroll
  for (int a = 0; a < 8; ++a)
    #pragma unroll
    for (int b = 0; b < 4; ++b) acc[a][b] = (f32x4){0.f, 0.f, 0.f, 0.f};

  // ---- prologue: tile0 (A0,A1,B0,B1) + tile1 (B0,B1); A(1) staged in-loop --
  stage_Ah<MODE>(A, Acr, Ksz, i0, 0, 0, As, tid);
  stage_Ah<MODE>(A, Acr, Ksz, i0, 0, 1, As, tid);
  stage_Bh(Bh, Ksz, n0, 0, 0, Ws, tid);
  stage_Bh(Bh, Ksz, n0, 0, 1, Ws, tid);
  stage_Bh(Bh, Ksz, n0, 1, 0, Ws + 16384, tid);
  stage_Bh(Bh, Ksz, n0, 1, 1, Ws + 16384, tid);
  asm volatile("s_waitcnt vmcnt(4)" ::: "memory");   // tile0 landed; B(1) in flight
  __builtin_amdgcn_s_barrier();
  __builtin_amdgcn_sched_barrier(0);

  for (int tt = 0; tt < nkt; ++tt) {
    const int cur = tt & 1;
    const u16* Ab = As + cur * 16384;
    const u16* Wb = Ws + cur * 16384;
    u16* An = As + (cur ^ 1) * 16384;    // A of tile tt+1
    u16* Wn = Ws + cur * 16384;          // B of tile tt+2 ((tt+2)&1 == cur)

    bf16x8 a[4][2], b[2][2], b2[2][2];

    // ---- P1: read A rt0-3 (8) + B ct0-1 (4); stage A0(tt+1) ----
    #pragma unroll
    for (int rt = 0; rt < 4; ++rt) {
      int ar = wr + rt * 16 + lr;
      a[rt][0] = ldsfrag(Ab, ar, lq);
      a[rt][1] = ldsfrag(Ab, ar, 4 + lq);
    }
    #pragma unroll
    for (int ct = 0; ct < 2; ++ct) {
      int br = wc + ct * 16 + lr;
      b[ct][0] = ldsfrag(Wb, br, lq);
      b[ct][1] = ldsfrag(Wb, br, 4 + lq);
    }
    if (tt + 1 < nkt) stage_Ah<MODE>(A, Acr, Ksz, i0, tt + 1, 0, An, tid);
    PHASE_MID();
    #pragma unroll
    for (int rt = 0; rt < 4; ++rt)
      #pragma unroll
      for (int ct = 0; ct < 2; ++ct) {
        acc[rt][ct] = __builtin_amdgcn_mfma_f32_16x16x32_bf16(a[rt][0], b[ct][0], acc[rt][ct], 0, 0, 0);
        acc[rt][ct] = __builtin_amdgcn_mfma_f32_16x16x32_bf16(a[rt][1], b[ct][1], acc[rt][ct], 0, 0, 0);
      }
    PHASE_END();

    // ---- P2: read B ct2-3 (4); stage A1(tt+1) ----
    #pragma unroll
    for (int ct = 0; ct < 2; ++ct) {
      int br = wc + (ct + 2) * 16 + lr;
      b2[ct][0] = ldsfrag(Wb, br, lq);
      b2[ct][1] = ldsfrag(Wb, br, 4 + lq);
    }
    if (tt + 1 < nkt) stage_Ah<MODE>(A, Acr, Ksz, i0, tt + 1, 1, An, tid);
    PHASE_MID();
    #pragma unroll
    for (int rt = 0; rt < 4; ++rt)
      #pragma unroll
      for (int ct = 0; ct < 2; ++ct) {
        acc[rt][ct + 2] = __builtin_amdgcn_mfma_f32_16x16x32_bf16(a[rt][0], b2[ct][0], acc[rt][ct + 2], 0, 0, 0);
        acc[rt][ct + 2] = __builtin_amdgcn_mfma_f32_16x16x32_bf16(a[rt][1], b2[ct][1], acc[rt][ct + 2], 0, 0, 0);
      }
    PHASE_END();

    // ---- P3: read A rt4-7 (8, reuse regs); stage B0(tt+2) ----
    #pragma unroll
    for (int rt = 0; rt < 4; ++rt) {
      int ar = wr + (rt + 4) * 16 + lr;
      a[rt][0] = ldsfrag(Ab, ar, lq);
      a[rt][1] = ldsfrag(Ab, ar, 4 + lq);
    }
    if (tt + 2 < nkt) stage_Bh(Bh, Ksz, n0, tt + 2, 0, Wn, tid);
    PHASE_MID();
    #pragma unroll
    for (int rt = 0; rt < 4; ++rt)
      #pragma unroll
      for (int ct = 0; ct < 2; ++ct) {
        acc[rt + 4][ct + 2] = __builtin_amdgcn_mfma_f32_16x16x32_bf16(a[rt][0], b2[ct][0], acc[rt + 4][ct + 2], 0, 0, 0);
        acc[rt + 4][ct + 2] = __builtin_amdgcn_mfma_f32_16x16x32_bf16(a[rt][1], b2[ct][1], acc[rt + 4][ct + 2], 0, 0, 0);
      }
    PHASE_END();

    // ---- P4: no reads; stage B1(tt+2); counted drain ----
    if (tt + 2 < nkt) stage_Bh(Bh, Ksz, n0, tt + 2, 1, Wn, tid);
    if (tt == nkt - 2) { asm volatile("s_waitcnt vmcnt(0)" ::: "memory"); }
    else               { asm volatile("s_waitcnt vmcnt(4)" ::: "memory"); }
    PHASE_MID();
    #pragma unroll
    for (int rt = 0; rt < 4; ++rt)
      #pragma unroll
      for (int ct = 0; ct < 2; ++ct) {
        acc[rt + 4][ct] = __builtin_amdgcn_mfma_f32_16x16x32_bf16(a[rt][0], b[ct][0], acc[rt + 4][ct], 0, 0, 0);
        acc[rt + 4][ct] = __builtin_amdgcn_mfma_f32_16x16x32_bf16(a[rt][1], b[ct][1], acc[rt + 4][ct], 0, 0, 0);
      }
    PHASE_END();
  }

  // ---- epilogue ----
  #pragma unroll
  for (int rt = 0; rt < 8; ++rt) {
    #pragma unroll
    for (int ct = 0; ct < 4; ++ct) {
      int col = n0 + wc + ct * 16 + lr;
      #pragma unroll
      for (int reg = 0; reg < 4; ++reg) {
        int row = i0 + wr + rt * 16 + lq * 4 + reg;
        float yv = acc[rt][ct][reg];
        if (MODE == 0) {
          float t = yv + bias[col];
          t = t / (1.f + __expf(-t));            // silu
          Cbf[(size_t)row * Nsz + col] = f2bf(t);
        } else {
          int b = col >> 8, d = col & 255;       // col = b*256 + d
          size_t ui = ((size_t)row * NB + b) * ND1 + (size_t)blockIdx.z * NHD + d;
          float uv = bf2f(Cbf[ui]);
          Cbf[ui] = f2bf(uv * yv);               // z = u * y, in place
        }
      }
    }
  }
}

// ---------------- 128x128 MFMA GEMM (kept for MODE 2 output GEMM) -----------
template <int MODE>
__global__ __launch_bounds__(256) void gemm_kernel(
    const u16* __restrict__ A, const u16* __restrict__ Bw,
    const float* __restrict__ bias, const float* __restrict__ resid,
    u16* __restrict__ Cbf, float* __restrict__ Cf,
    int Msz, int Nsz, int Ksz) {
  __shared__ __align__(16) u16 As[128 * 64];
  __shared__ __align__(16) u16 Ws[128 * 64];

  const int tid = threadIdx.x;
  const int lane = tid & 63, wave = tid >> 6;
  const int wr = (wave >> 1) * 64, wc = (wave & 1) * 64;
  const int lr = lane & 15, lq = lane >> 4;
  const int i0 = blockIdx.y * 128, n0 = blockIdx.x * 128;

  f32x4 acc[4][4];
  #pragma unroll
  for (int a = 0; a < 4; ++a)
    #pragma unroll
    for (int b = 0; b < 4; ++b) acc[a][b] = (f32x4){0.f, 0.f, 0.f, 0.f};

  const int nkt = Ksz >> 6;
  for (int kt = 0; kt < nkt; ++kt) {
    #pragma unroll
    for (int it = 0; it < 4; ++it) {
      int vv = tid + 256 * it;
      int r = vv >> 3, c8 = vv & 7;
      int c8s = c8 ^ (r & 7);
      gl_lds16(A + (size_t)(i0 + r) * Ksz + kt * 64 + c8s * 8,
               &As[(size_t)(wave * 64 + it * 256) * 8]);
    }
    #pragma unroll
    for (int it = 0; it < 4; ++it) {
      int vv = tid + 256 * it;
      int r = vv >> 3, c8 = vv & 7;
      int c8s = c8 ^ (r & 7);
      gl_lds16(Bw + (size_t)(n0 + r) * Ksz + kt * 64 + c8s * 8,
               &Ws[(size_t)(wave * 64 + it * 256) * 8]);
    }
    __syncthreads();
    #pragma unroll
    for (int ks = 0; ks < 2; ++ks) {
      bf16x8 af[4], bfr[4];
      #pragma unroll
      for (int rt = 0; rt < 4; ++rt) {
        int ar = wr + rt * 16 + lr;
        int cq = (ks * 4 + lq) ^ (ar & 7);
        af[rt] = *(const bf16x8*)&As[ar * 64 + cq * 8];
      }
      #pragma unroll
      for (int ct = 0; ct < 4; ++ct) {
        int br = wc + ct * 16 + lr;
        int cq = (ks * 4 + lq) ^ (br & 7);
        bfr[ct] = *(const bf16x8*)&Ws[br * 64 + cq * 8];
      }
      #pragma unroll
      for (int rt = 0; rt < 4; ++rt)
        #pragma unroll
        for (int ct = 0; ct < 4; ++ct)
          acc[rt][ct] = __builtin_amdgcn_mfma_f32_16x16x32_bf16(
              af[rt], bfr[ct], acc[rt][ct], 0, 0, 0);
    }
    __syncthreads();
  }

  #pragma unroll
  for (int rt = 0; rt < 4; ++rt) {
    #pragma unroll
    for (int ct = 0; ct < 4; ++ct) {
      int col = n0 + wc + ct * 16 + lr;
      #pragma unroll
      for (int reg = 0; reg < 4; ++reg) {
        int row = i0 + wr + rt * 16 + lq * 4 + reg;
        float yv = acc[rt][ct][reg];
        size_t oi = (size_t)row * Nsz + col;
        Cf[oi] = yv + bias[col] + resid[oi];
      }
    }
  }
}

extern "C" void kernel_launch(void* const* d_in, const int* in_sizes, int n_in,
                              void* d_out, int out_size, void* d_ws, size_t ws_size,
                              hipStream_t stream) {
  const float* q    = (const float*)d_in[0];
  const float* uw   = (const float*)d_in[3];
  const float* ub   = (const float*)d_in[4];
  const float* vw   = (const float*)d_in[5];
  const float* vb   = (const float*)d_in[6];
  const float* ow   = (const float*)d_in[7];
  const float* ob   = (const float*)d_in[8];
  const float* pos  = (const float*)d_in[9];
  const float* zero = (const float*)d_in[10];
  const float* neg  = (const float*)d_in[11];
  float* out = (float*)d_out;

  char* ws = (char*)d_ws;
  u16* x   = (u16*)(ws + 0);            // 8192x1024 bf16 = 16 MiB
  u16* uwb = (u16*)(ws + 16777216);     // 4 MiB
  u16* vwb = (u16*)(ws + 20971520);     // 4 MiB
  u16* owb = (u16*)(ws + 25165824);     // 4 MiB
  u16* u   = (u16*)(ws + 29360128);     // 8192x2048 bf16 = 32 MiB (later z)
  u16* v   = (u16*)(ws + 62914560);     // 32 MiB
  u16* vT  = (u16*)(ws + 96468992);     // 32 MiB
  u16* cr8 = (u16*)(ws + 130023424);    // 8*8*4104*2 = 513 KiB

  // allow 128 KiB dynamic LDS for the 8-phase kernels
  hipFuncSetAttribute((const void*)gemm256<0>,
                      hipFuncAttributeMaxDynamicSharedMemorySize, 131072);
  hipFuncSetAttribute((const void*)gemm256<1>,
                      hipFuncAttributeMaxDynamicSharedMemorySize, 131072);

  cvt_kernel<<<2048, 256, 0, stream>>>(uw, uwb, 524288);
  cvt_kernel<<<2048, 256, 0, stream>>>(vw, vwb, 524288);
  cvt_kernel<<<2048, 256, 0, stream>>>(ow, owb, 524288);
  build_cr8<<<64, 256, 0, stream>>>(pos, zero, neg, cr8);
  rmsnorm_kernel<<<NM, 256, 0, stream>>>(q, x);

  // u = silu(x @ uw^T + ub), v = silu(x @ vw^T + vb)   (256^2 8-phase)
  gemm256<0><<<dim3(8, 32, 1), 512, 131072, stream>>>(x, uwb, ub, u, NM, ND1, NE);
  gemm256<0><<<dim3(8, 32, 1), 512, 131072, stream>>>(x, vwb, vb, v, NM, ND1, NE);
  // vT[h][b*256+d][j] = v[(j,b)][h*256+d]
  transpose_v<<<dim3(32, 4, 32), 256, 0, stream>>>(v, vT);
  // per head: y = T_h @ vT_h^T ; z = u*y in place (in u buffer)
  gemm256<1><<<dim3(4, 8, 8), 512, 131072, stream>>>(cr8, vT, nullptr, u,
                                                     LSEQ, NB * NHD, LSEQ);
  // out = z @ ow^T + ob + q   (128^2 kernel, full-grid occupancy)
  gemm_kernel<2><<<dim3(8, 64, 1), 256, 0, stream>>>(u, owb, ob, q, nullptr, out,
                                                     NM, NE, ND1);
}

// Round 5
// 368.507 us; speedup vs baseline: 1.2203x; 1.0126x over previous
//
#include <hip/hip_runtime.h>
#include <math.h>

typedef unsigned short u16;
typedef __bf16 bf16x8 __attribute__((ext_vector_type(8)));
typedef float f32x4 __attribute__((ext_vector_type(4)));

#define LSEQ 2048
#define NB   4
#define NE   1024
#define NHEAD 8
#define ND1  2048
#define NHD  256
#define NM   8192          // LSEQ*NB
#define CRP  4104          // pitch of shifted-coeff rows (elements, mult of 8)

__device__ __forceinline__ u16 f2bf(float f) {
  unsigned u = __float_as_uint(f);
  u += 0x7FFFu + ((u >> 16) & 1u);       // RTNE
  return (u16)(u >> 16);
}
__device__ __forceinline__ float bf2f(u16 h) {
  return __uint_as_float(((unsigned)h) << 16);
}
__device__ __forceinline__ unsigned mulbf2(unsigned y2, unsigned u2) {
  float ylo = bf2f((u16)(y2 & 0xFFFF)), yhi = bf2f((u16)(y2 >> 16));
  float ulo = bf2f((u16)(u2 & 0xFFFF)), uhi = bf2f((u16)(u2 >> 16));
  return (unsigned)f2bf(ylo * ulo) | ((unsigned)f2bf(yhi * uhi) << 16);
}

// async global->LDS, 16B per lane; LDS dest is wave-uniform base + lane*16B
__device__ __forceinline__ void gl_lds16(const u16* g, u16* l) {
  __builtin_amdgcn_global_load_lds(
      (const __attribute__((address_space(1))) void*)g,
      (__attribute__((address_space(3))) void*)l, 16, 0, 0);
}

// ---------------- prep: 3x f32->bf16 weight convert + toeplitz cr8 ----------
// blocks 0..6143: cvt (2048 each for uw/vw/ow); blocks 6144..6207: build cr8.
__global__ __launch_bounds__(256) void prep_kernel(
    const float* __restrict__ uw, const float* __restrict__ vw,
    const float* __restrict__ ow, u16* __restrict__ uwb, u16* __restrict__ vwb,
    u16* __restrict__ owb, const float* __restrict__ pos,
    const float* __restrict__ zero, const float* __restrict__ neg,
    u16* __restrict__ cr8) {
  int bx = blockIdx.x;
  if (bx < 6144) {
    const float* s = bx < 2048 ? uw : (bx < 4096 ? vw : ow);
    u16* d = bx < 2048 ? uwb : (bx < 4096 ? vwb : owb);
    int i = (bx & 2047) * 256 + threadIdx.x;
    float4 v = ((const float4*)s)[i];
    ushort4 o;
    o.x = f2bf(v.x); o.y = f2bf(v.y); o.z = f2bf(v.z); o.w = f2bf(v.w);
    ((ushort4*)d)[i] = o;
  } else {
    int bb = bx - 6144;
    int h = bb >> 3, sh = bb & 7;
    u16* out = cr8 + (size_t)bb * CRP;
    for (int m = threadIdx.x; m < CRP; m += 256) {
      int mm = m + sh;
      float val = 0.f;
      if (mm <= 4094) {
        int t = 2047 - mm;                // t = i - j
        if (t == 0)      val = zero[h];
        else if (t > 0)  val = pos[h * (LSEQ - 1) + t - 1];
        else             val = neg[h * (LSEQ - 1) + (-t) - 1];
      }
      out[m] = f2bf(val);
    }
  }
}

// ---------------- RMSNorm: x = q / (||q||/sqrt(E) + 1e-8), bf16 out ----------
__global__ __launch_bounds__(256) void rmsnorm_kernel(const float* __restrict__ q,
                                                      u16* __restrict__ x) {
  int row = blockIdx.x;
  float4 v = ((const float4*)(q + (size_t)row * NE))[threadIdx.x];
  float ss = v.x * v.x + v.y * v.y + v.z * v.z + v.w * v.w;
  #pragma unroll
  for (int off = 32; off > 0; off >>= 1) ss += __shfl_down(ss, off, 64);
  __shared__ float wss[4];
  int wave = threadIdx.x >> 6, lane = threadIdx.x & 63;
  if (lane == 0) wss[wave] = ss;
  __syncthreads();
  float tot = wss[0] + wss[1] + wss[2] + wss[3];
  float scale = 1.f / (sqrtf(tot) * 0.03125f + 1e-8f);
  ushort4 o;
  o.x = f2bf(v.x * scale); o.y = f2bf(v.y * scale);
  o.z = f2bf(v.z * scale); o.w = f2bf(v.w * scale);
  ((ushort4*)(x + (size_t)row * NE))[threadIdx.x] = o;
}

// ------- transpose v (rows (j,b), cols (h,d)) -> vT[h][b*256+d][j], ushort4 --
__global__ __launch_bounds__(256) void transpose_v(const u16* __restrict__ v,
                                                   u16* __restrict__ vT) {
  __shared__ u16 s[64 * 68];
  int j0 = blockIdx.x * 64, d0 = blockIdx.y * 64;
  int h = blockIdx.z >> 2, b = blockIdx.z & 3;
  #pragma unroll
  for (int it = 0; it < 4; ++it) {
    int idx = it * 256 + threadIdx.x;          // 0..1023
    int r = idx >> 4, c4 = idx & 15;           // row 0..63, col-quad 0..15
    *(ushort4*)&s[r * 68 + c4 * 4] =
        *(const ushort4*)&v[((size_t)(j0 + r) * NB + b) * ND1 + h * NHD + d0 + c4 * 4];
  }
  __syncthreads();
  #pragma unroll
  for (int it = 0; it < 4; ++it) {
    int idx = it * 256 + threadIdx.x;
    int cc = idx >> 4, jq = idx & 15;          // out-row 0..63, j-quad 0..15
    ushort4 o;
    o.x = s[(jq * 4 + 0) * 68 + cc];
    o.y = s[(jq * 4 + 1) * 68 + cc];
    o.z = s[(jq * 4 + 2) * 68 + cc];
    o.w = s[(jq * 4 + 3) * 68 + cc];
    *(ushort4*)&vT[((size_t)h * (NB * NHD) + b * NHD + d0 + cc) * LSEQ + j0 + jq * 4] = o;
  }
}

// ================= 256x256 2-phase-per-tile GEMM (T2+T4+T5) ==================
// 8 waves (2Mx4N), wave-tile 128x64, BK=64, 128 KiB LDS double-buffer.
// XOR chunk swizzle (source-side + ds_read side, round-2: 0 conflicts).
// PH1: read A rt0-3 + B ct0-3 (16 ds_read); stage A(tt+1) both halves;
//      barrier; lgkm; 32 MFMA (acc[0..3][*]); barrier.
// PH2: read A rt4-7 (8 ds_read, reuse regs); stage B(tt+2) both halves
//      (into Wb slot, dead after PH1's barrier); vmcnt(4); barrier; lgkm;
//      32 MFMA (acc[4..7][*]); barrier.
// vmcnt ledger: entry(tt) in-flight B(tt+1)=4; +A(tt+1)=8; +B(tt+2)=12;
// vmcnt(4) retires B(tt+1)+A(tt+1). vmcnt(0) only at tt==nkt-2.
// Epilogue: acc -> LDS (XOR ((row>>2)&3)<<4) -> coalesced 16B/lane pass.

__device__ __forceinline__ bf16x8 ldsfrag(const u16* buf, int rr, int q) {
  return *(const bf16x8*)(buf + rr * 64 + ((q ^ (rr & 7)) * 8));
}

template <int MODE>
__device__ __forceinline__ void stage_Ah(const u16* A, const u16* Acr, int Ksz,
                                         int i0, int kt, int half, u16* dstbuf,
                                         int tid) {
  int wave = tid >> 6;
  #pragma unroll
  for (int it = 0; it < 2; ++it) {
    int vv = it * 512 + tid;               // 0..1023
    int r = vv >> 3, c8 = vv & 7, c8s = c8 ^ (r & 7);
    int row = i0 + half * 128 + r;
    const u16* src;
    if (MODE != 1) {
      src = A + (size_t)row * Ksz + kt * 64 + c8s * 8;
    } else {
      int p = 2047 - row + kt * 64;        // cr index of column 0
      int s = p & 7, qq = p - s;           // 8-aligned base in copy s
      src = Acr + (size_t)s * CRP + qq + c8s * 8;
    }
    gl_lds16(src, dstbuf + half * 8192 + (it * 512 + wave * 64) * 8);
  }
}

__device__ __forceinline__ void stage_Bh(const u16* B, int Ksz, int n0, int kt,
                                         int half, u16* dstbuf, int tid) {
  int wave = tid >> 6;
  #pragma unroll
  for (int it = 0; it < 2; ++it) {
    int vv = it * 512 + tid;
    int r = vv >> 3, c8 = vv & 7, c8s = c8 ^ (r & 7);
    gl_lds16(B + (size_t)(n0 + half * 128 + r) * Ksz + kt * 64 + c8s * 8,
             dstbuf + half * 8192 + (it * 512 + wave * 64) * 8);
  }
}

#define PHASE_MID()                                        \
  __builtin_amdgcn_s_barrier();                            \
  asm volatile("s_waitcnt lgkmcnt(0)" ::: "memory");       \
  __builtin_amdgcn_sched_barrier(0);                       \
  __builtin_amdgcn_s_setprio(1);

#define PHASE_END()                                        \
  __builtin_amdgcn_s_setprio(0);                           \
  __builtin_amdgcn_s_barrier();                            \
  __builtin_amdgcn_sched_barrier(0);

// MODE 0: z-dispatch picks (Bw0,bias0,C0) or (Bw1,bias1,C1); C = silu(acc+b)
// MODE 1: A from cr8 (toeplitz), z = head; epilogue C0[ui] = u[ui] * acc
template <int MODE>
__global__ __launch_bounds__(512, 2) void gemm256(
    const u16* __restrict__ A, const u16* __restrict__ Bw0,
    const u16* __restrict__ Bw1, const float* __restrict__ bias0,
    const float* __restrict__ bias1, u16* __restrict__ C0,
    u16* __restrict__ C1, int Msz, int Nsz, int Ksz) {
  extern __shared__ __align__(16) u16 lds[];
  u16* As = lds;             // 2 buf x 256 x 64 = 32768 u16
  u16* Ws = lds + 32768;     // 2 buf x 256 x 64

  const int tid = threadIdx.x;
  const int lane = tid & 63, wave = tid >> 6;
  const int wr = (wave >> 2) * 128, wc = (wave & 3) * 64;
  const int lr = lane & 15, lq = lane >> 4;
  const int i0 = blockIdx.y * 256, n0 = blockIdx.x * 256;

  const u16* Bh;
  const u16* Acr = A;
  const float* bias = bias0;
  u16* Cp = C0;
  if (MODE == 0) {
    Bh = blockIdx.z ? Bw1 : Bw0;
    bias = blockIdx.z ? bias1 : bias0;
    Cp = blockIdx.z ? C1 : C0;
  } else {
    Bh  = Bw0 + (size_t)blockIdx.z * Nsz * Ksz;   // vT head base
    Acr = A + (size_t)blockIdx.z * 8 * CRP;       // cr8 head base
  }
  const int nkt = Ksz >> 6;

  f32x4 acc[8][4];
  #pragma unroll
  for (int a = 0; a < 8; ++a)
    #pragma unroll
    for (int b = 0; b < 4; ++b) acc[a][b] = (f32x4){0.f, 0.f, 0.f, 0.f};

  // ---- prologue: A(0),B(0),B(1) staged; A(1) staged in-loop ----
  stage_Ah<MODE>(A, Acr, Ksz, i0, 0, 0, As, tid);
  stage_Ah<MODE>(A, Acr, Ksz, i0, 0, 1, As, tid);
  stage_Bh(Bh, Ksz, n0, 0, 0, Ws, tid);
  stage_Bh(Bh, Ksz, n0, 0, 1, Ws, tid);
  stage_Bh(Bh, Ksz, n0, 1, 0, Ws + 16384, tid);
  stage_Bh(Bh, Ksz, n0, 1, 1, Ws + 16384, tid);
  asm volatile("s_waitcnt vmcnt(4)" ::: "memory");   // tile0 landed; B(1) in flight
  __builtin_amdgcn_s_barrier();
  __builtin_amdgcn_sched_barrier(0);

  for (int tt = 0; tt < nkt; ++tt) {
    const int cur = tt & 1;
    const u16* Ab = As + cur * 16384;
    const u16* Wb = Ws + cur * 16384;
    u16* An = As + (cur ^ 1) * 16384;    // A of tile tt+1
    u16* Wn = Ws + cur * 16384;          // B of tile tt+2 ((tt+2)&1 == cur)

    bf16x8 a[4][2], b[4][2];

    // ---- PH1: read A rt0-3 (8) + B ct0-3 (8); stage A(tt+1) h0+h1 ----
    #pragma unroll
    for (int rt = 0; rt < 4; ++rt) {
      int ar = wr + rt * 16 + lr;
      a[rt][0] = ldsfrag(Ab, ar, lq);
      a[rt][1] = ldsfrag(Ab, ar, 4 + lq);
    }
    #pragma unroll
    for (int ct = 0; ct < 4; ++ct) {
      int br = wc + ct * 16 + lr;
      b[ct][0] = ldsfrag(Wb, br, lq);
      b[ct][1] = ldsfrag(Wb, br, 4 + lq);
    }
    if (tt + 1 < nkt) {
      stage_Ah<MODE>(A, Acr, Ksz, i0, tt + 1, 0, An, tid);
      stage_Ah<MODE>(A, Acr, Ksz, i0, tt + 1, 1, An, tid);
    }
    PHASE_MID();
    #pragma unroll
    for (int rt = 0; rt < 4; ++rt)
      #pragma unroll
      for (int ct = 0; ct < 4; ++ct) {
        acc[rt][ct] = __builtin_amdgcn_mfma_f32_16x16x32_bf16(a[rt][0], b[ct][0], acc[rt][ct], 0, 0, 0);
        acc[rt][ct] = __builtin_amdgcn_mfma_f32_16x16x32_bf16(a[rt][1], b[ct][1], acc[rt][ct], 0, 0, 0);
      }
    PHASE_END();

    // ---- PH2: read A rt4-7 (8, reuse regs); stage B(tt+2) h0+h1; vmcnt ----
    #pragma unroll
    for (int rt = 0; rt < 4; ++rt) {
      int ar = wr + (rt + 4) * 16 + lr;
      a[rt][0] = ldsfrag(Ab, ar, lq);
      a[rt][1] = ldsfrag(Ab, ar, 4 + lq);
    }
    if (tt + 2 < nkt) {
      stage_Bh(Bh, Ksz, n0, tt + 2, 0, Wn, tid);
      stage_Bh(Bh, Ksz, n0, tt + 2, 1, Wn, tid);
    }
    if (tt == nkt - 2) { asm volatile("s_waitcnt vmcnt(0)" ::: "memory"); }
    else               { asm volatile("s_waitcnt vmcnt(4)" ::: "memory"); }
    PHASE_MID();
    #pragma unroll
    for (int rt = 0; rt < 4; ++rt)
      #pragma unroll
      for (int ct = 0; ct < 4; ++ct) {
        acc[rt + 4][ct] = __builtin_amdgcn_mfma_f32_16x16x32_bf16(a[rt][0], b[ct][0], acc[rt + 4][ct], 0, 0, 0);
        acc[rt + 4][ct] = __builtin_amdgcn_mfma_f32_16x16x32_bf16(a[rt][1], b[ct][1], acc[rt + 4][ct], 0, 0, 0);
      }
    PHASE_END();
  }

  // ---- epilogue: acc -> LDS (swizzled) -> coalesced global pass ----
  // all gl_lds drained (vmcnt(0) at nkt-2; none staged after); ds_reads retired.
  __syncthreads();
  u16* zl = lds;                           // [256][256] bf16 = 128 KiB
  #pragma unroll
  for (int rt = 0; rt < 8; ++rt) {
    #pragma unroll
    for (int ct = 0; ct < 4; ++ct) {
      int col_l = wc + ct * 16 + lr;
      #pragma unroll
      for (int reg = 0; reg < 4; ++reg) {
        int row_l = wr + rt * 16 + lq * 4 + reg;
        float yv = acc[rt][ct][reg];
        if (MODE == 0) {
          float t = yv + bias[n0 + col_l];
          yv = t / (1.f + __expf(-t));     // silu
        }
        zl[row_l * 256 + (col_l ^ (((row_l >> 2) & 3) << 4))] = f2bf(yv);
      }
    }
  }
  __syncthreads();
  #pragma unroll
  for (int k = 0; k < 16; ++k) {
    int cc = k * 512 + tid;                // 0..8191 16B-chunks
    int row_l = cc >> 5, c8 = cc & 31;
    int colbase = c8 * 8;
    int swz = colbase ^ (((row_l >> 2) & 3) << 4);
    uint4 y4 = *(uint4*)&zl[row_l * 256 + swz];
    if (MODE == 0) {
      *(uint4*)&Cp[(size_t)(i0 + row_l) * Nsz + n0 + colbase] = y4;
    } else {
      // col = n0 + colbase; b = blockIdx.x (256 cols per b), d = colbase
      size_t ui = ((size_t)(i0 + row_l) * NB + blockIdx.x) * ND1 +
                  (size_t)blockIdx.z * NHD + colbase;
      uint4 u4 = *(const uint4*)&Cp[ui];
      uint4 o;
      o.x = mulbf2(y4.x, u4.x); o.y = mulbf2(y4.y, u4.y);
      o.z = mulbf2(y4.z, u4.z); o.w = mulbf2(y4.w, u4.w);
      *(uint4*)&Cp[ui] = o;
    }
  }
}

// ---------------- 128x128 MFMA GEMM: out = z @ ow^T + ob + q  (f32) ----------
__global__ __launch_bounds__(256) void gemm_out(
    const u16* __restrict__ A, const u16* __restrict__ Bw,
    const float* __restrict__ bias, const float* __restrict__ resid,
    float* __restrict__ Cf, int Nsz, int Ksz) {
  __shared__ __align__(16) u16 As[128 * 64];
  __shared__ __align__(16) u16 Ws[128 * 64];

  const int tid = threadIdx.x;
  const int lane = tid & 63, wave = tid >> 6;
  const int wr = (wave >> 1) * 64, wc = (wave & 1) * 64;
  const int lr = lane & 15, lq = lane >> 4;
  const int i0 = blockIdx.y * 128, n0 = blockIdx.x * 128;

  f32x4 acc[4][4];
  #pragma unroll
  for (int a = 0; a < 4; ++a)
    #pragma unroll
    for (int b = 0; b < 4; ++b) acc[a][b] = (f32x4){0.f, 0.f, 0.f, 0.f};

  const int nkt = Ksz >> 6;
  for (int kt = 0; kt < nkt; ++kt) {
    #pragma unroll
    for (int it = 0; it < 4; ++it) {
      int vv = tid + 256 * it;
      int r = vv >> 3, c8 = vv & 7;
      int c8s = c8 ^ (r & 7);
      gl_lds16(A + (size_t)(i0 + r) * Ksz + kt * 64 + c8s * 8,
               &As[(size_t)(wave * 64 + it * 256) * 8]);
    }
    #pragma unroll
    for (int it = 0; it < 4; ++it) {
      int vv = tid + 256 * it;
      int r = vv >> 3, c8 = vv & 7;
      int c8s = c8 ^ (r & 7);
      gl_lds16(Bw + (size_t)(n0 + r) * Ksz + kt * 64 + c8s * 8,
               &Ws[(size_t)(wave * 64 + it * 256) * 8]);
    }
    __syncthreads();
    #pragma unroll
    for (int ks = 0; ks < 2; ++ks) {
      bf16x8 af[4], bfr[4];
      #pragma unroll
      for (int rt = 0; rt < 4; ++rt) {
        int ar = wr + rt * 16 + lr;
        int cq = (ks * 4 + lq) ^ (ar & 7);
        af[rt] = *(const bf16x8*)&As[ar * 64 + cq * 8];
      }
      #pragma unroll
      for (int ct = 0; ct < 4; ++ct) {
        int br = wc + ct * 16 + lr;
        int cq = (ks * 4 + lq) ^ (br & 7);
        bfr[ct] = *(const bf16x8*)&Ws[br * 64 + cq * 8];
      }
      #pragma unroll
      for (int rt = 0; rt < 4; ++rt)
        #pragma unroll
        for (int ct = 0; ct < 4; ++ct)
          acc[rt][ct] = __builtin_amdgcn_mfma_f32_16x16x32_bf16(
              af[rt], bfr[ct], acc[rt][ct], 0, 0, 0);
    }
    __syncthreads();
  }

  #pragma unroll
  for (int rt = 0; rt < 4; ++rt) {
    #pragma unroll
    for (int ct = 0; ct < 4; ++ct) {
      int col = n0 + wc + ct * 16 + lr;
      #pragma unroll
      for (int reg = 0; reg < 4; ++reg) {
        int row = i0 + wr + rt * 16 + lq * 4 + reg;
        size_t oi = (size_t)row * Nsz + col;
        Cf[oi] = acc[rt][ct][reg] + bias[col] + resid[oi];
      }
    }
  }
}

extern "C" void kernel_launch(void* const* d_in, const int* in_sizes, int n_in,
                              void* d_out, int out_size, void* d_ws, size_t ws_size,
                              hipStream_t stream) {
  const float* q    = (const float*)d_in[0];
  const float* uw   = (const float*)d_in[3];
  const float* ub   = (const float*)d_in[4];
  const float* vw   = (const float*)d_in[5];
  const float* vb   = (const float*)d_in[6];
  const float* ow   = (const float*)d_in[7];
  const float* ob   = (const float*)d_in[8];
  const float* pos  = (const float*)d_in[9];
  const float* zero = (const float*)d_in[10];
  const float* neg  = (const float*)d_in[11];
  float* out = (float*)d_out;

  char* ws = (char*)d_ws;
  u16* x   = (u16*)(ws + 0);            // 8192x1024 bf16 = 16 MiB
  u16* uwb = (u16*)(ws + 16777216);     // 4 MiB
  u16* vwb = (u16*)(ws + 20971520);     // 4 MiB
  u16* owb = (u16*)(ws + 25165824);     // 4 MiB
  u16* u   = (u16*)(ws + 29360128);     // 8192x2048 bf16 = 32 MiB (later z)
  u16* v   = (u16*)(ws + 62914560);     // 32 MiB
  u16* vT  = (u16*)(ws + 96468992);     // 32 MiB
  u16* cr8 = (u16*)(ws + 130023424);    // 8*8*4104*2 = 513 KiB

  // allow 128 KiB dynamic LDS for the 2-phase 256^2 kernels
  hipFuncSetAttribute((const void*)gemm256<0>,
                      hipFuncAttributeMaxDynamicSharedMemorySize, 131072);
  hipFuncSetAttribute((const void*)gemm256<1>,
                      hipFuncAttributeMaxDynamicSharedMemorySize, 131072);

  prep_kernel<<<6208, 256, 0, stream>>>(uw, vw, ow, uwb, vwb, owb,
                                        pos, zero, neg, cr8);
  rmsnorm_kernel<<<NM, 256, 0, stream>>>(q, x);

  // u = silu(x @ uw^T + ub), v = silu(x @ vw^T + vb)  (one launch, z picks)
  gemm256<0><<<dim3(8, 32, 2), 512, 131072, stream>>>(x, uwb, vwb, ub, vb, u, v,
                                                      NM, ND1, NE);
  // vT[h][b*256+d][j] = v[(j,b)][h*256+d]
  transpose_v<<<dim3(32, 4, 32), 256, 0, stream>>>(v, vT);
  // per head: y = T_h @ vT_h^T ; z = u*y in place (in u buffer)
  gemm256<1><<<dim3(4, 8, 8), 512, 131072, stream>>>(cr8, vT, nullptr, nullptr,
                                                     nullptr, u, nullptr,
                                                     LSEQ, NB * NHD, LSEQ);
  // out = z @ ow^T + ob + q
  gemm_out<<<dim3(8, 64, 1), 256, 0, stream>>>(u, owb, ob, q, out, NE, ND1);
}

// Round 7
// 361.404 us; speedup vs baseline: 1.2442x; 1.0197x over previous
//
#include <hip/hip_runtime.h>
#include <math.h>

typedef unsigned short u16;
typedef __bf16 bf16x8 __attribute__((ext_vector_type(8)));
typedef float f32x4 __attribute__((ext_vector_type(4)));

#define LSEQ 2048
#define NB   4
#define NE   1024
#define NHEAD 8
#define ND1  2048
#define NHD  256
#define NM   8192          // LSEQ*NB
#define CRP  4104          // pitch of shifted-coeff rows (elements, mult of 8)

__device__ __forceinline__ u16 f2bf(float f) {
  unsigned u = __float_as_uint(f);
  u += 0x7FFFu + ((u >> 16) & 1u);       // RTNE
  return (u16)(u >> 16);
}
__device__ __forceinline__ float bf2f(u16 h) {
  return __uint_as_float(((unsigned)h) << 16);
}
__device__ __forceinline__ unsigned mulbf2(unsigned y2, unsigned u2) {
  float ylo = bf2f((u16)(y2 & 0xFFFF)), yhi = bf2f((u16)(y2 >> 16));
  float ulo = bf2f((u16)(u2 & 0xFFFF)), uhi = bf2f((u16)(u2 >> 16));
  return (unsigned)f2bf(ylo * ulo) | ((unsigned)f2bf(yhi * uhi) << 16);
}

// async global->LDS, 16B per lane; LDS dest is wave-uniform base + lane*16B
__device__ __forceinline__ void gl_lds16(const u16* g, u16* l) {
  __builtin_amdgcn_global_load_lds(
      (const __attribute__((address_space(1))) void*)g,
      (__attribute__((address_space(3))) void*)l, 16, 0, 0);
}

// ---------------- prep: 3x f32->bf16 weight convert + toeplitz cr8 ----------
__global__ __launch_bounds__(256) void prep_kernel(
    const float* __restrict__ uw, const float* __restrict__ vw,
    const float* __restrict__ ow, u16* __restrict__ uwb, u16* __restrict__ vwb,
    u16* __restrict__ owb, const float* __restrict__ pos,
    const float* __restrict__ zero, const float* __restrict__ neg,
    u16* __restrict__ cr8) {
  int bx = blockIdx.x;
  if (bx < 6144) {
    const float* s = bx < 2048 ? uw : (bx < 4096 ? vw : ow);
    u16* d = bx < 2048 ? uwb : (bx < 4096 ? vwb : owb);
    int i = (bx & 2047) * 256 + threadIdx.x;
    float4 v = ((const float4*)s)[i];
    ushort4 o;
    o.x = f2bf(v.x); o.y = f2bf(v.y); o.z = f2bf(v.z); o.w = f2bf(v.w);
    ((ushort4*)d)[i] = o;
  } else {
    int bb = bx - 6144;
    int h = bb >> 3, sh = bb & 7;
    u16* out = cr8 + (size_t)bb * CRP;
    for (int m = threadIdx.x; m < CRP; m += 256) {
      int mm = m + sh;
      float val = 0.f;
      if (mm <= 4094) {
        int t = 2047 - mm;                // t = i - j
        if (t == 0)      val = zero[h];
        else if (t > 0)  val = pos[h * (LSEQ - 1) + t - 1];
        else             val = neg[h * (LSEQ - 1) + (-t) - 1];
      }
      out[m] = f2bf(val);
    }
  }
}

// ---------------- RMSNorm: x = q / (||q||/sqrt(E) + 1e-8), bf16 out ----------
__global__ __launch_bounds__(256) void rmsnorm_kernel(const float* __restrict__ q,
                                                      u16* __restrict__ x) {
  int row = blockIdx.x;
  float4 v = ((const float4*)(q + (size_t)row * NE))[threadIdx.x];
  float ss = v.x * v.x + v.y * v.y + v.z * v.z + v.w * v.w;
  #pragma unroll
  for (int off = 32; off > 0; off >>= 1) ss += __shfl_down(ss, off, 64);
  __shared__ float wss[4];
  int wave = threadIdx.x >> 6, lane = threadIdx.x & 63;
  if (lane == 0) wss[wave] = ss;
  __syncthreads();
  float tot = wss[0] + wss[1] + wss[2] + wss[3];
  float scale = 1.f / (sqrtf(tot) * 0.03125f + 1e-8f);
  ushort4 o;
  o.x = f2bf(v.x * scale); o.y = f2bf(v.y * scale);
  o.z = f2bf(v.z * scale); o.w = f2bf(v.w * scale);
  ((ushort4*)(x + (size_t)row * NE))[threadIdx.x] = o;
}

// ================= 256x256 2-phase GEMM, 3-deep A ring (160 KiB LDS) =========
// 8 waves (2Mx4N), wave-tile 128x64, BK=64.
// LDS: A ring x3 (96 KiB) + B dbuf x2 (64 KiB) = 160 KiB (full CU).
// XOR chunk swizzle on stage-source + ds_read (verified 0 conflicts, r2).
// PH1: read A rt0-3 + B ct0-3 (16 ds_read); stage A(tt+2) -> slot (tt+2)%3;
//      barrier; lgkm; 32 MFMA; barrier.
// PH2: read A rt4-7 (8); stage B(tt+2) -> slot tt&1 (B(tt) dead after PH1);
//      vmcnt(8) [retires A(tt+1)+B(tt+1), both issued a FULL TILE earlier];
//      barrier; lgkm; 32 MFMA; barrier.
// vmcnt(0) only at tt==nkt-2. Prologue: A0,B0,A1,B1 then vmcnt(8).

__device__ __forceinline__ bf16x8 ldsfrag(const u16* buf, int rr, int q) {
  return *(const bf16x8*)(buf + rr * 64 + ((q ^ (rr & 7)) * 8));
}

template <int MODE>
__device__ __forceinline__ void stage_Ah(const u16* A, const u16* Acr, int Ksz,
                                         int i0, int kt, int half, u16* dstbuf,
                                         int tid) {
  int wave = tid >> 6;
  #pragma unroll
  for (int it = 0; it < 2; ++it) {
    int vv = it * 512 + tid;               // 0..1023
    int r = vv >> 3, c8 = vv & 7, c8s = c8 ^ (r & 7);
    int row = i0 + half * 128 + r;
    const u16* src;
    if (MODE != 1) {
      src = A + (size_t)row * Ksz + kt * 64 + c8s * 8;
    } else {
      int p = 2047 - row + kt * 64;        // cr index of column 0
      int s = p & 7, qq = p - s;           // 8-aligned base in copy s
      src = Acr + (size_t)s * CRP + qq + c8s * 8;
    }
    gl_lds16(src, dstbuf + half * 8192 + (it * 512 + wave * 64) * 8);
  }
}

__device__ __forceinline__ void stage_Bh(const u16* B, int Ksz, int n0, int kt,
                                         int half, u16* dstbuf, int tid) {
  int wave = tid >> 6;
  #pragma unroll
  for (int it = 0; it < 2; ++it) {
    int vv = it * 512 + tid;
    int r = vv >> 3, c8 = vv & 7, c8s = c8 ^ (r & 7);
    gl_lds16(B + (size_t)(n0 + half * 128 + r) * Ksz + kt * 64 + c8s * 8,
             dstbuf + half * 8192 + (it * 512 + wave * 64) * 8);
  }
}

#define PHASE_MID()                                        \
  __builtin_amdgcn_s_barrier();                            \
  asm volatile("s_waitcnt lgkmcnt(0)" ::: "memory");       \
  __builtin_amdgcn_sched_barrier(0);                       \
  __builtin_amdgcn_s_setprio(1);

#define PHASE_END()                                        \
  __builtin_amdgcn_s_setprio(0);                           \
  __builtin_amdgcn_s_barrier();                            \
  __builtin_amdgcn_sched_barrier(0);

// MODE 0: z=0 -> C0 = u = silu(x@uw^T+ub); z=1 -> writes vT DIRECTLY
//         (transposed epilogue): vT[h=bx][b*256+d][j] = silu(x@vw^T+vb)
// MODE 1: A from cr8 (toeplitz); epilogue C0[ui] = u[ui] * acc (z=u*y)
template <int MODE>
__global__ __launch_bounds__(512, 2) void gemm256(
    const u16* __restrict__ A, const u16* __restrict__ Bw0,
    const u16* __restrict__ Bw1, const float* __restrict__ bias0,
    const float* __restrict__ bias1, u16* __restrict__ C0,
    u16* __restrict__ C1, int Msz, int Nsz, int Ksz) {
  extern __shared__ __align__(16) u16 lds[];
  u16* As = lds;             // 3 slots x 256x64 = 49152 u16 (96 KiB)
  u16* Ws = lds + 49152;     // 2 slots x 256x64 = 32768 u16 (64 KiB)

  // ---- bijective XCD swizzle (nwg % 8 == 0 for all launches) ----
  unsigned gx = gridDim.x, gy = gridDim.y;
  unsigned nwg = gx * gy * gridDim.z;
  unsigned lin = blockIdx.x + gx * (blockIdx.y + gy * blockIdx.z);
  unsigned w = (lin & 7) * (nwg >> 3) + (lin >> 3);
  unsigned bx = w % gx, rest = w / gx;
  unsigned by = rest % gy, bz = rest / gy;

  const int tid = threadIdx.x;
  const int lane = tid & 63, wave = tid >> 6;
  const int wr = (wave >> 2) * 128, wc = (wave & 3) * 64;
  const int lr = lane & 15, lq = lane >> 4;
  const int i0 = by * 256, n0 = bx * 256;

  const u16* Bh;
  const u16* Acr = A;
  const float* bias = bias0;
  u16* Cp = C0;
  if (MODE == 0) {
    Bh = bz ? Bw1 : Bw0;
    bias = bz ? bias1 : bias0;
    Cp = bz ? C1 : C0;
  } else {
    Bh  = Bw0 + (size_t)bz * Nsz * Ksz;   // vT head base
    Acr = A + (size_t)bz * 8 * CRP;       // cr8 head base
  }
  const int nkt = Ksz >> 6;

  f32x4 acc[8][4];
  #pragma unroll
  for (int a = 0; a < 8; ++a)
    #pragma unroll
    for (int b = 0; b < 4; ++b) acc[a][b] = (f32x4){0.f, 0.f, 0.f, 0.f};

  // ---- prologue: A(0),B(0),A(1),B(1); wait tile0 (8 oldest) ----
  stage_Ah<MODE>(A, Acr, Ksz, i0, 0, 0, As, tid);
  stage_Ah<MODE>(A, Acr, Ksz, i0, 0, 1, As, tid);
  stage_Bh(Bh, Ksz, n0, 0, 0, Ws, tid);
  stage_Bh(Bh, Ksz, n0, 0, 1, Ws, tid);
  stage_Ah<MODE>(A, Acr, Ksz, i0, 1, 0, As + 16384, tid);
  stage_Ah<MODE>(A, Acr, Ksz, i0, 1, 1, As + 16384, tid);
  stage_Bh(Bh, Ksz, n0, 1, 0, Ws + 16384, tid);
  stage_Bh(Bh, Ksz, n0, 1, 1, Ws + 16384, tid);
  asm volatile("s_waitcnt vmcnt(8)" ::: "memory");   // A0,B0 landed
  __builtin_amdgcn_s_barrier();
  __builtin_amdgcn_sched_barrier(0);

  for (int tt = 0; tt < nkt; ++tt) {
    const u16* Ab = As + (tt % 3) * 16384;
    const u16* Wb = Ws + (tt & 1) * 16384;
    u16* An = As + ((tt + 2) % 3) * 16384;   // A of tile tt+2 (slot free)
    u16* Wn = Ws + (tt & 1) * 16384;         // B of tile tt+2 (B(tt) dead after PH1)

    bf16x8 a[4][2], b[4][2];

    // ---- PH1: read A rt0-3 (8) + B ct0-3 (8); stage A(tt+2) ----
    #pragma unroll
    for (int rt = 0; rt < 4; ++rt) {
      int ar = wr + rt * 16 + lr;
      a[rt][0] = ldsfrag(Ab, ar, lq);
      a[rt][1] = ldsfrag(Ab, ar, 4 + lq);
    }
    #pragma unroll
    for (int ct = 0; ct < 4; ++ct) {
      int br = wc + ct * 16 + lr;
      b[ct][0] = ldsfrag(Wb, br, lq);
      b[ct][1] = ldsfrag(Wb, br, 4 + lq);
    }
    if (tt + 2 < nkt) {
      stage_Ah<MODE>(A, Acr, Ksz, i0, tt + 2, 0, An, tid);
      stage_Ah<MODE>(A, Acr, Ksz, i0, tt + 2, 1, An, tid);
    }
    PHASE_MID();
    #pragma unroll
    for (int rt = 0; rt < 4; ++rt)
      #pragma unroll
      for (int ct = 0; ct < 4; ++ct) {
        acc[rt][ct] = __builtin_amdgcn_mfma_f32_16x16x32_bf16(a[rt][0], b[ct][0], acc[rt][ct], 0, 0, 0);
        acc[rt][ct] = __builtin_amdgcn_mfma_f32_16x16x32_bf16(a[rt][1], b[ct][1], acc[rt][ct], 0, 0, 0);
      }
    PHASE_END();

    // ---- PH2: read A rt4-7 (8); stage B(tt+2); counted vmcnt ----
    #pragma unroll
    for (int rt = 0; rt < 4; ++rt) {
      int ar = wr + (rt + 4) * 16 + lr;
      a[rt][0] = ldsfrag(Ab, ar, lq);
      a[rt][1] = ldsfrag(Ab, ar, 4 + lq);
    }
    if (tt + 2 < nkt) {
      stage_Bh(Bh, Ksz, n0, tt + 2, 0, Wn, tid);
      stage_Bh(Bh, Ksz, n0, tt + 2, 1, Wn, tid);
    }
    if (tt == nkt - 2) { asm volatile("s_waitcnt vmcnt(0)" ::: "memory"); }
    else               { asm volatile("s_waitcnt vmcnt(8)" ::: "memory"); }
    PHASE_MID();
    #pragma unroll
    for (int rt = 0; rt < 4; ++rt)
      #pragma unroll
      for (int ct = 0; ct < 4; ++ct) {
        acc[rt + 4][ct] = __builtin_amdgcn_mfma_f32_16x16x32_bf16(a[rt][0], b[ct][0], acc[rt + 4][ct], 0, 0, 0);
        acc[rt + 4][ct] = __builtin_amdgcn_mfma_f32_16x16x32_bf16(a[rt][1], b[ct][1], acc[rt + 4][ct], 0, 0, 0);
      }
    PHASE_END();
  }

  // ---- epilogue ----
  __syncthreads();
  if (MODE == 0 && bz == 1) {
    // v-path: silu -> TRANSPOSED LDS -> direct vT write (head h = bx)
    // store (row,col=d) at zt[d*256 + (row ^ (row>>4) ^ ((d&15)<<2))]
    u16* zt = lds;
    #pragma unroll
    for (int rt = 0; rt < 8; ++rt) {
      #pragma unroll
      for (int ct = 0; ct < 4; ++ct) {
        int col_l = wc + ct * 16 + lr;
        #pragma unroll
        for (int reg = 0; reg < 4; ++reg) {
          int row_l = wr + rt * 16 + lq * 4 + reg;
          float t = acc[rt][ct][reg] + bias[n0 + col_l];
          t = t / (1.f + __expf(-t));
          zt[col_l * 256 + (row_l ^ (row_l >> 4) ^ ((col_l & 15) << 2))] = f2bf(t);
        }
      }
    }
    __syncthreads();
    int j0 = by * 64;
    #pragma unroll
    for (int it2 = 0; it2 < 32; ++it2) {
      int g = it2 * 512 + tid;
      int jq = g & 15, b2 = (g >> 4) & 3, d = g >> 6;
      int rl0 = 16 * jq + b2, sd = (d & 15) << 2;
      ushort4 o;
      o.x = zt[d * 256 + ((rl0 + 0)  ^ ((rl0 + 0)  >> 4) ^ sd)];
      o.y = zt[d * 256 + ((rl0 + 4)  ^ ((rl0 + 4)  >> 4) ^ sd)];
      o.z = zt[d * 256 + ((rl0 + 8)  ^ ((rl0 + 8)  >> 4) ^ sd)];
      o.w = zt[d * 256 + ((rl0 + 12) ^ ((rl0 + 12) >> 4) ^ sd)];
      *(ushort4*)&Cp[((size_t)bx * (NB * NHD) + b2 * NHD + d) * LSEQ + j0 + jq * 4] = o;
    }
    return;
  }
  // u-path / mode-1: linear-swizzled LDS -> coalesced 16B pass
  u16* zl = lds;                           // [256][256] bf16 = 128 KiB
  #pragma unroll
  for (int rt = 0; rt < 8; ++rt) {
    #pragma unroll
    for (int ct = 0; ct < 4; ++ct) {
      int col_l = wc + ct * 16 + lr;
      #pragma unroll
      for (int reg = 0; reg < 4; ++reg) {
        int row_l = wr + rt * 16 + lq * 4 + reg;
        float yv = acc[rt][ct][reg];
        if (MODE == 0) {
          float t = yv + bias[n0 + col_l];
          yv = t / (1.f + __expf(-t));     // silu
        }
        zl[row_l * 256 + (col_l ^ (((row_l >> 2) & 3) << 4))] = f2bf(yv);
      }
    }
  }
  __syncthreads();
  #pragma unroll
  for (int k = 0; k < 16; ++k) {
    int cc = k * 512 + tid;                // 0..8191 16B-chunks
    int row_l = cc >> 5, c8 = cc & 31;
    int colbase = c8 * 8;
    int swz = colbase ^ (((row_l >> 2) & 3) << 4);
    uint4 y4 = *(uint4*)&zl[row_l * 256 + swz];
    if (MODE == 0) {
      *(uint4*)&Cp[(size_t)(i0 + row_l) * Nsz + n0 + colbase] = y4;
    } else {
      size_t ui = ((size_t)(i0 + row_l) * NB + bx) * ND1 +
                  (size_t)bz * NHD + colbase;
      uint4 u4 = *(const uint4*)&Cp[ui];
      uint4 o;
      o.x = mulbf2(y4.x, u4.x); o.y = mulbf2(y4.y, u4.y);
      o.z = mulbf2(y4.z, u4.z); o.w = mulbf2(y4.w, u4.w);
      *(uint4*)&Cp[ui] = o;
    }
  }
}

// ---------------- 128x128 MFMA GEMM: out = z @ ow^T + ob + q  (f32) ----------
__global__ __launch_bounds__(256) void gemm_out(
    const u16* __restrict__ A, const u16* __restrict__ Bw,
    const float* __restrict__ bias, const float* __restrict__ resid,
    float* __restrict__ Cf, int Nsz, int Ksz) {
  __shared__ __align__(16) u16 As[128 * 64];
  __shared__ __align__(16) u16 Ws[128 * 64];

  unsigned gx = gridDim.x, gy = gridDim.y;
  unsigned nwg = gx * gy;
  unsigned lin = blockIdx.x + gx * blockIdx.y;
  unsigned w = (lin & 7) * (nwg >> 3) + (lin >> 3);
  unsigned bx = w % gx, by = w / gx;

  const int tid = threadIdx.x;
  const int lane = tid & 63, wave = tid >> 6;
  const int wr = (wave >> 1) * 64, wc = (wave & 1) * 64;
  const int lr = lane & 15, lq = lane >> 4;
  const int i0 = by * 128, n0 = bx * 128;

  f32x4 acc[4][4];
  #pragma unroll
  for (int a = 0; a < 4; ++a)
    #pragma unroll
    for (int b = 0; b < 4; ++b) acc[a][b] = (f32x4){0.f, 0.f, 0.f, 0.f};

  const int nkt = Ksz >> 6;
  for (int kt = 0; kt < nkt; ++kt) {
    #pragma unroll
    for (int it = 0; it < 4; ++it) {
      int vv = tid + 256 * it;
      int r = vv >> 3, c8 = vv & 7;
      int c8s = c8 ^ (r & 7);
      gl_lds16(A + (size_t)(i0 + r) * Ksz + kt * 64 + c8s * 8,
               &As[(size_t)(wave * 64 + it * 256) * 8]);
    }
    #pragma unroll
    for (int it = 0; it < 4; ++it) {
      int vv = tid + 256 * it;
      int r = vv >> 3, c8 = vv & 7;
      int c8s = c8 ^ (r & 7);
      gl_lds16(Bw + (size_t)(n0 + r) * Ksz + kt * 64 + c8s * 8,
               &Ws[(size_t)(wave * 64 + it * 256) * 8]);
    }
    __syncthreads();
    #pragma unroll
    for (int ks = 0; ks < 2; ++ks) {
      bf16x8 af[4], bfr[4];
      #pragma unroll
      for (int rt = 0; rt < 4; ++rt) {
        int ar = wr + rt * 16 + lr;
        int cq = (ks * 4 + lq) ^ (ar & 7);
        af[rt] = *(const bf16x8*)&As[ar * 64 + cq * 8];
      }
      #pragma unroll
      for (int ct = 0; ct < 4; ++ct) {
        int br = wc + ct * 16 + lr;
        int cq = (ks * 4 + lq) ^ (br & 7);
        bfr[ct] = *(const bf16x8*)&Ws[br * 64 + cq * 8];
      }
      #pragma unroll
      for (int rt = 0; rt < 4; ++rt)
        #pragma unroll
        for (int ct = 0; ct < 4; ++ct)
          acc[rt][ct] = __builtin_amdgcn_mfma_f32_16x16x32_bf16(
              af[rt], bfr[ct], acc[rt][ct], 0, 0, 0);
    }
    __syncthreads();
  }

  #pragma unroll
  for (int rt = 0; rt < 4; ++rt) {
    #pragma unroll
    for (int ct = 0; ct < 4; ++ct) {
      int col = n0 + wc + ct * 16 + lr;
      #pragma unroll
      for (int reg = 0; reg < 4; ++reg) {
        int row = i0 + wr + rt * 16 + lq * 4 + reg;
        size_t oi = (size_t)row * Nsz + col;
        Cf[oi] = acc[rt][ct][reg] + bias[col] + resid[oi];
      }
    }
  }
}

extern "C" void kernel_launch(void* const* d_in, const int* in_sizes, int n_in,
                              void* d_out, int out_size, void* d_ws, size_t ws_size,
                              hipStream_t stream) {
  const float* q    = (const float*)d_in[0];
  const float* uw   = (const float*)d_in[3];
  const float* ub   = (const float*)d_in[4];
  const float* vw   = (const float*)d_in[5];
  const float* vb   = (const float*)d_in[6];
  const float* ow   = (const float*)d_in[7];
  const float* ob   = (const float*)d_in[8];
  const float* pos  = (const float*)d_in[9];
  const float* zero = (const float*)d_in[10];
  const float* neg  = (const float*)d_in[11];
  float* out = (float*)d_out;

  char* ws = (char*)d_ws;
  u16* x   = (u16*)(ws + 0);            // 8192x1024 bf16 = 16 MiB
  u16* uwb = (u16*)(ws + 16777216);     // 4 MiB
  u16* vwb = (u16*)(ws + 20971520);     // 4 MiB
  u16* owb = (u16*)(ws + 25165824);     // 4 MiB
  u16* u   = (u16*)(ws + 29360128);     // 8192x2048 bf16 = 32 MiB (later z)
  u16* vT  = (u16*)(ws + 96468992);     // 32 MiB (v materialized only as vT)
  u16* cr8 = (u16*)(ws + 130023424);    // 8*8*4104*2 = 513 KiB

  // 160 KiB dynamic LDS (3-deep A ring + B dbuf)
  hipFuncSetAttribute((const void*)gemm256<0>,
                      hipFuncAttributeMaxDynamicSharedMemorySize, 163840);
  hipFuncSetAttribute((const void*)gemm256<1>,
                      hipFuncAttributeMaxDynamicSharedMemorySize, 163840);

  prep_kernel<<<6208, 256, 0, stream>>>(uw, vw, ow, uwb, vwb, owb,
                                        pos, zero, neg, cr8);
  rmsnorm_kernel<<<NM, 256, 0, stream>>>(q, x);

  // z=0: u = silu(x@uw^T+ub) -> u ; z=1: silu(x@vw^T+vb) -> vT (transposed)
  gemm256<0><<<dim3(8, 32, 2), 512, 163840, stream>>>(x, uwb, vwb, ub, vb, u, vT,
                                                      NM, ND1, NE);
  // per head: y = T_h @ vT_h^T ; z = u*y in place (in u buffer)
  gemm256<1><<<dim3(4, 8, 8), 512, 163840, stream>>>(cr8, vT, nullptr, nullptr,
                                                     nullptr, u, nullptr,
                                                     LSEQ, NB * NHD, LSEQ);
  // out = z @ ow^T + ob + q
  gemm_out<<<dim3(8, 64, 1), 256, 0, stream>>>(u, owb, ob, q, out, NE, ND1);
}